// Round 1
// baseline (324.220 us; speedup 1.0000x reference)
//
#include <hip/hip_runtime.h>

// DualTimeConstantHighPassMixAdaptation on MI355X (gfx950)
// x: [B=8, C=64, T=64000] fp32. 512 independent dual-EMA scans along T.
//
// R4: occupancy push. R3 was latency-bound at 2 waves/SIMD (Occupancy 17%,
// VALUBusy 19%, HBM 31%): ~8000 cyc/tile with only ~900 cyc of VALU work.
//  - Single wave-private LDS buffer (6.4 KB): the 25 inputs are fully in
//    registers before phase-2 staging, and same-wave LDS ops are in-order,
//    so output staging reuses the input tile. 25.6 KB/block (was 51.2).
//  - SEGS_W 4 -> 8: 1024 blocks = 4 blocks/CU = 16 waves/CU (2x waves;
//    halo stays 6400 samples -> identical accuracy, work x1.31).
//  - __launch_bounds__(256,4) pins the 16-waves/CU VGPR budget (<=128).
//  - Global stores moved AFTER the prefetch commit: the vmcnt wait before
//    the commit ds_writes now only covers loads issued ~900 cyc earlier
//    (plus last tile's stores), never the just-issued stores.

#define THREADS 256
#define WPB 4                     // waves per block
#define K 25                      // floats per lane per tile
#define WTILE (64 * K)            // 1600 floats = 6.4 KB per wave-tile
#define T_LEN 64000
#define SEGS_W 8
#define SEG_LEN (T_LEN / SEGS_W)  // 8000 floats
#define SEG_TILES (SEG_LEN / WTILE) // 5
#define HALO_TILES 4              // 6400-float halo (a_slow^6400 ~ 1.3e-3)
#define EPS_V 1e-6f

__global__ __launch_bounds__(THREADS, 4)
void dual_ema_hp_kernel(const float* __restrict__ x,
                        const float* __restrict__ p_mu_fast,
                        const float* __restrict__ p_mu_slow,
                        const float* __restrict__ p_mwa,
                        const float* __restrict__ p_mhp,
                        float* __restrict__ out)
{
    __shared__ float lds[WPB * WTILE];       // 25.6 KB/block -> 6 blocks/CU LDS cap
    const int tid  = threadIdx.x;
    const int lane = tid & 63;
    const int wv   = tid >> 6;
    float* buf = &lds[wv * WTILE];           // wave-private tile (in AND out staging)

    const int gw  = blockIdx.x * WPB + wv;
    const int row = gw / SEGS_W;
    const int seg = gw % SEGS_W;
    const int h   = (seg == 0) ? 0 : HALO_TILES;
    const int nt  = SEG_TILES + h;

    const float* gseg = x   + (size_t)row * T_LEN + (size_t)seg * SEG_LEN - (size_t)h * WTILE;
    float*       oseg = out + (size_t)row * T_LEN + (size_t)seg * SEG_LEN - (size_t)h * WTILE;

    const float mu_f = p_mu_fast[0];
    const float mu_s = p_mu_slow[0];
    const float af = 1.0f - mu_f;
    const float as = 1.0f - mu_s;
    const float wa  = 1.0f / (1.0f + __expf(-p_mwa[0]));   // sigmoid(mix_weight_adapt)
    const float wb  = 1.0f - wa;
    const float whp = 1.0f / (1.0f + __expf(-p_mhp[0]));   // sigmoid(mix_weight_hp)

    // chunk decay (25 samples) + powers for the shfl_up scan
    const float Pf1  = __powf(af, (float)K);
    const float Ps1  = __powf(as, (float)K);
    const float Pf2  = Pf1 * Pf1,   Ps2  = Ps1 * Ps1;
    const float Pf4  = Pf2 * Pf2,   Ps4  = Ps2 * Ps2;
    const float Pf8  = Pf4 * Pf4,   Ps8  = Ps4 * Ps4;
    const float Pf16 = Pf8 * Pf8,   Ps16 = Ps8 * Ps8;
    const float Pf32 = Pf16 * Pf16, Ps32 = Ps16 * Ps16;

    // ---- prologue: load tile 0 coalesced into regs, stage to LDS ----
    float4 p0, p1, p2, p3, p4, p5; float ps;
    {
        const float4* g4 = (const float4*)gseg;
        p0 = g4[0 * 64 + lane]; p1 = g4[1 * 64 + lane]; p2 = g4[2 * 64 + lane];
        p3 = g4[3 * 64 + lane]; p4 = g4[4 * 64 + lane]; p5 = g4[5 * 64 + lane];
        ps = gseg[1536 + lane];
    }
    {
        float4* i4 = (float4*)buf;
        i4[0 * 64 + lane] = p0; i4[1 * 64 + lane] = p1; i4[2 * 64 + lane] = p2;
        i4[3 * 64 + lane] = p3; i4[4 * 64 + lane] = p4; i4[5 * 64 + lane] = p5;
        buf[1536 + lane] = ps;
    }

    float sfr = 0.0f, ssr = 0.0f;   // wave's carried EMA state (zero at halo start)

    for (int t = 0; t < nt; ++t) {
        // ---- make prev ds_writes visible cross-lane, read my 25-elem chunk ----
        asm volatile("s_waitcnt lgkmcnt(0)" ::: "memory");
        float y[K];
#pragma unroll
        for (int i = 0; i < K; ++i)
            y[i] = fmaxf(buf[lane * K + i], 0.0f);   // stride 25: 2-way alias, free

        // ---- issue prefetch for tile t+1 (regs; committed at loop end) ----
        const bool pref = (t + 1 < nt);
        if (pref) {
            const float* gt = gseg + (size_t)(t + 1) * WTILE;
            const float4* g4 = (const float4*)gt;
            p0 = g4[0 * 64 + lane]; p1 = g4[1 * 64 + lane]; p2 = g4[2 * 64 + lane];
            p3 = g4[3 * 64 + lane]; p4 = g4[4 * 64 + lane]; p5 = g4[5 * 64 + lane];
            ps = gt[1536 + lane];
        }

        // first sample of the whole row: init-at-first-sample == incoming state y0
        if (seg == 0 && t == 0 && lane == 0) { sfr = y[0]; ssr = y[0]; }

        // ---- phase 1: per-lane local scan (lane0 seeded with carried state) ----
        float inf = (lane == 0) ? sfr : 0.0f;
        float ins = (lane == 0) ? ssr : 0.0f;
        float mf = fmaf(af, inf, mu_f * y[0]);
        float ms = fmaf(as, ins, mu_s * y[0]);
#pragma unroll
        for (int i = 1; i < K; ++i) {
            mf = fmaf(af, mf, mu_f * y[i]);
            ms = fmaf(as, ms, mu_s * y[i]);
        }

        // ---- wave inclusive scan of carries: S_l = c_l + P * S_{l-1} ----
        float cf = mf, cs = ms, uf, us;
        uf = __shfl_up(cf, 1);  us = __shfl_up(cs, 1);
        cf = (lane >= 1)  ? fmaf(Pf1,  uf, cf) : cf;  cs = (lane >= 1)  ? fmaf(Ps1,  us, cs) : cs;
        uf = __shfl_up(cf, 2);  us = __shfl_up(cs, 2);
        cf = (lane >= 2)  ? fmaf(Pf2,  uf, cf) : cf;  cs = (lane >= 2)  ? fmaf(Ps2,  us, cs) : cs;
        uf = __shfl_up(cf, 4);  us = __shfl_up(cs, 4);
        cf = (lane >= 4)  ? fmaf(Pf4,  uf, cf) : cf;  cs = (lane >= 4)  ? fmaf(Ps4,  us, cs) : cs;
        uf = __shfl_up(cf, 8);  us = __shfl_up(cs, 8);
        cf = (lane >= 8)  ? fmaf(Pf8,  uf, cf) : cf;  cs = (lane >= 8)  ? fmaf(Ps8,  us, cs) : cs;
        uf = __shfl_up(cf, 16); us = __shfl_up(cs, 16);
        cf = (lane >= 16) ? fmaf(Pf16, uf, cf) : cf;  cs = (lane >= 16) ? fmaf(Ps16, us, cs) : cs;
        uf = __shfl_up(cf, 32); us = __shfl_up(cs, 32);
        cf = (lane >= 32) ? fmaf(Pf32, uf, cf) : cf;  cs = (lane >= 32) ? fmaf(Ps32, us, cs) : cs;

        // exclusive value = state entering my chunk; lane0 <- carried state
        float ex_f = __shfl_up(cf, 1), ex_s = __shfl_up(cs, 1);
        if (lane == 0) { ex_f = sfr; ex_s = ssr; }
        // state after this tile (broadcast from lane 63)
        sfr = __shfl(cf, 63);
        ssr = __shfl(cs, 63);

        const bool emit = (t >= h);
        float4 s0, s1, s2, s3, s4, s5; float ss;
        if (emit) {
            // ---- phase 2: re-scan with correct state, stage output to LDS ----
            float mf2 = ex_f, ms2 = ex_s;
#pragma unroll
            for (int i = 0; i < K; ++i) {
                float yv = y[i];
                mf2 = fmaf(af, mf2, mu_f * yv);
                ms2 = fmaf(as, ms2, mu_s * yv);
                float M = fmaf(wa, mf2, wb * ms2);
                float o = yv * __builtin_amdgcn_rcpf(EPS_V + M) + whp * (yv - M);
                buf[lane * K + i] = o;                 // overwrite consumed input tile
            }
            asm volatile("s_waitcnt lgkmcnt(0)" ::: "memory");  // cross-lane flush

            // ---- read transposed outputs back to regs (before commit clobbers) --
            const float4* o4 = (const float4*)buf;
            s0 = o4[0 * 64 + lane]; s1 = o4[1 * 64 + lane]; s2 = o4[2 * 64 + lane];
            s3 = o4[3 * 64 + lane]; s4 = o4[4 * 64 + lane]; s5 = o4[5 * 64 + lane];
            ss = buf[1536 + lane];
        }

        // ---- commit prefetched tile t+1 (vmcnt wait covers ONLY the loads;
        //      this tile's stores haven't been issued yet) ----
        if (pref) {
            float4* i4 = (float4*)buf;
            i4[0 * 64 + lane] = p0; i4[1 * 64 + lane] = p1; i4[2 * 64 + lane] = p2;
            i4[3 * 64 + lane] = p3; i4[4 * 64 + lane] = p4; i4[5 * 64 + lane] = p5;
            buf[1536 + lane] = ps;
        }

        // ---- coalesced store, issued last ----
        if (emit) {
            float* gout = oseg + (size_t)t * WTILE;
            float4* go4 = (float4*)gout;
            go4[0 * 64 + lane] = s0;
            go4[1 * 64 + lane] = s1;
            go4[2 * 64 + lane] = s2;
            go4[3 * 64 + lane] = s3;
            go4[4 * 64 + lane] = s4;
            go4[5 * 64 + lane] = s5;
            gout[1536 + lane] = ss;
        }
    }
}

extern "C" void kernel_launch(void* const* d_in, const int* in_sizes, int n_in,
                              void* d_out, int out_size, void* d_ws, size_t ws_size,
                              hipStream_t stream) {
    const float* x    = (const float*)d_in[0];
    const float* mu_f = (const float*)d_in[1];
    const float* mu_s = (const float*)d_in[2];
    const float* mwa  = (const float*)d_in[3];
    const float* mhp  = (const float*)d_in[4];
    float* out = (float*)d_out;

    const int rows   = in_sizes[0] / T_LEN;          // 512
    const int blocks = rows * SEGS_W / WPB;          // 1024
    dual_ema_hp_kernel<<<blocks, THREADS, 0, stream>>>(x, mu_f, mu_s, mwa, mhp, out);
}

// Round 2
// 322.488 us; speedup vs baseline: 1.0054x; 1.0054x over previous
//
#include <hip/hip_runtime.h>

// DualTimeConstantHighPassMixAdaptation on MI355X (gfx950)
// x: [B=8, C=64, T=64000] fp32. 512 independent dual-EMA scans along T.
//
// R5: R4 minus the register spills.
// R4 post-mortem: WRITE_SIZE 128000->302080 KiB (+174 MB = scratch spill
// stores; ~20 floats/lane/tile), VGPR_Count 80->64. With
// __launch_bounds__(256,4) (min-waves form) LLVM squeezed into the 64-reg
// band (8 waves/EU) and spilled ~20 slots; the single-buffer structure needs
// ~100 live VGPRs (y[25]+p[25]+s[25]+state). Spill reads hit L2 (FETCH was
// exactly the halo prediction) but dirty spill lines evicted to HBM.
// Fix: pin waves/EU to exactly 4 via amdgpu_waves_per_eu(4,4) -> 128-reg
// band, no squeeze incentive. Max=4 is free: grid = 1024 blocks = 4
// blocks/CU = 16 waves/CU already.
//  - Single wave-private LDS buffer (6.4 KB): inputs fully in regs before
//    phase-2 staging; same-wave LDS pipe is in-order. 25.6 KB/block.
//  - SEGS_W=8: 1024 blocks = 4 blocks/CU = 16 waves/CU (halo 6400 samples,
//    a_slow^6400 ~ 1.3e-3 -> negligible at absmax threshold).
//  - Stores issued after the prefetch commit: the vmcnt wait before the
//    commit ds_writes covers only loads issued ~900 cyc earlier.

#define THREADS 256
#define WPB 4                     // waves per block
#define K 25                      // floats per lane per tile
#define WTILE (64 * K)            // 1600 floats = 6.4 KB per wave-tile
#define T_LEN 64000
#define SEGS_W 8
#define SEG_LEN (T_LEN / SEGS_W)  // 8000 floats
#define SEG_TILES (SEG_LEN / WTILE) // 5
#define HALO_TILES 4              // 6400-float halo (a_slow^6400 ~ 1.3e-3)
#define EPS_V 1e-6f

__global__ __attribute__((amdgpu_flat_work_group_size(THREADS, THREADS)))
__attribute__((amdgpu_waves_per_eu(4, 4)))
void dual_ema_hp_kernel(const float* __restrict__ x,
                        const float* __restrict__ p_mu_fast,
                        const float* __restrict__ p_mu_slow,
                        const float* __restrict__ p_mwa,
                        const float* __restrict__ p_mhp,
                        float* __restrict__ out)
{
    __shared__ float lds[WPB * WTILE];       // 25.6 KB/block
    const int tid  = threadIdx.x;
    const int lane = tid & 63;
    const int wv   = tid >> 6;
    float* buf = &lds[wv * WTILE];           // wave-private tile (in AND out staging)

    const int gw  = blockIdx.x * WPB + wv;
    const int row = gw / SEGS_W;
    const int seg = gw % SEGS_W;
    const int h   = (seg == 0) ? 0 : HALO_TILES;
    const int nt  = SEG_TILES + h;

    const float* gseg = x   + (size_t)row * T_LEN + (size_t)seg * SEG_LEN - (size_t)h * WTILE;
    float*       oseg = out + (size_t)row * T_LEN + (size_t)seg * SEG_LEN - (size_t)h * WTILE;

    const float mu_f = p_mu_fast[0];
    const float mu_s = p_mu_slow[0];
    const float af = 1.0f - mu_f;
    const float as = 1.0f - mu_s;
    const float wa  = 1.0f / (1.0f + __expf(-p_mwa[0]));   // sigmoid(mix_weight_adapt)
    const float wb  = 1.0f - wa;
    const float whp = 1.0f / (1.0f + __expf(-p_mhp[0]));   // sigmoid(mix_weight_hp)

    // chunk decay (25 samples) + powers for the shfl_up scan
    const float Pf1  = __powf(af, (float)K);
    const float Ps1  = __powf(as, (float)K);
    const float Pf2  = Pf1 * Pf1,   Ps2  = Ps1 * Ps1;
    const float Pf4  = Pf2 * Pf2,   Ps4  = Ps2 * Ps2;
    const float Pf8  = Pf4 * Pf4,   Ps8  = Ps4 * Ps4;
    const float Pf16 = Pf8 * Pf8,   Ps16 = Ps8 * Ps8;
    const float Pf32 = Pf16 * Pf16, Ps32 = Ps16 * Ps16;

    // ---- prologue: load tile 0 coalesced into regs, stage to LDS ----
    float4 p0, p1, p2, p3, p4, p5; float ps;
    {
        const float4* g4 = (const float4*)gseg;
        p0 = g4[0 * 64 + lane]; p1 = g4[1 * 64 + lane]; p2 = g4[2 * 64 + lane];
        p3 = g4[3 * 64 + lane]; p4 = g4[4 * 64 + lane]; p5 = g4[5 * 64 + lane];
        ps = gseg[1536 + lane];
    }
    {
        float4* i4 = (float4*)buf;
        i4[0 * 64 + lane] = p0; i4[1 * 64 + lane] = p1; i4[2 * 64 + lane] = p2;
        i4[3 * 64 + lane] = p3; i4[4 * 64 + lane] = p4; i4[5 * 64 + lane] = p5;
        buf[1536 + lane] = ps;
    }

    float sfr = 0.0f, ssr = 0.0f;   // wave's carried EMA state (zero at halo start)

    for (int t = 0; t < nt; ++t) {
        // ---- make prev ds_writes visible cross-lane, read my 25-elem chunk ----
        asm volatile("s_waitcnt lgkmcnt(0)" ::: "memory");
        float y[K];
#pragma unroll
        for (int i = 0; i < K; ++i)
            y[i] = fmaxf(buf[lane * K + i], 0.0f);   // stride 25: 2-way alias, free

        // ---- issue prefetch for tile t+1 (regs; committed at loop end) ----
        const bool pref = (t + 1 < nt);
        if (pref) {
            const float* gt = gseg + (size_t)(t + 1) * WTILE;
            const float4* g4 = (const float4*)gt;
            p0 = g4[0 * 64 + lane]; p1 = g4[1 * 64 + lane]; p2 = g4[2 * 64 + lane];
            p3 = g4[3 * 64 + lane]; p4 = g4[4 * 64 + lane]; p5 = g4[5 * 64 + lane];
            ps = gt[1536 + lane];
        }

        // first sample of the whole row: init-at-first-sample == incoming state y0
        if (seg == 0 && t == 0 && lane == 0) { sfr = y[0]; ssr = y[0]; }

        // ---- phase 1: per-lane local scan (lane0 seeded with carried state) ----
        float inf = (lane == 0) ? sfr : 0.0f;
        float ins = (lane == 0) ? ssr : 0.0f;
        float mf = fmaf(af, inf, mu_f * y[0]);
        float ms = fmaf(as, ins, mu_s * y[0]);
#pragma unroll
        for (int i = 1; i < K; ++i) {
            mf = fmaf(af, mf, mu_f * y[i]);
            ms = fmaf(as, ms, mu_s * y[i]);
        }

        // ---- wave inclusive scan of carries: S_l = c_l + P * S_{l-1} ----
        float cf = mf, cs = ms, uf, us;
        uf = __shfl_up(cf, 1);  us = __shfl_up(cs, 1);
        cf = (lane >= 1)  ? fmaf(Pf1,  uf, cf) : cf;  cs = (lane >= 1)  ? fmaf(Ps1,  us, cs) : cs;
        uf = __shfl_up(cf, 2);  us = __shfl_up(cs, 2);
        cf = (lane >= 2)  ? fmaf(Pf2,  uf, cf) : cf;  cs = (lane >= 2)  ? fmaf(Ps2,  us, cs) : cs;
        uf = __shfl_up(cf, 4);  us = __shfl_up(cs, 4);
        cf = (lane >= 4)  ? fmaf(Pf4,  uf, cf) : cf;  cs = (lane >= 4)  ? fmaf(Ps4,  us, cs) : cs;
        uf = __shfl_up(cf, 8);  us = __shfl_up(cs, 8);
        cf = (lane >= 8)  ? fmaf(Pf8,  uf, cf) : cf;  cs = (lane >= 8)  ? fmaf(Ps8,  us, cs) : cs;
        uf = __shfl_up(cf, 16); us = __shfl_up(cs, 16);
        cf = (lane >= 16) ? fmaf(Pf16, uf, cf) : cf;  cs = (lane >= 16) ? fmaf(Ps16, us, cs) : cs;
        uf = __shfl_up(cf, 32); us = __shfl_up(cs, 32);
        cf = (lane >= 32) ? fmaf(Pf32, uf, cf) : cf;  cs = (lane >= 32) ? fmaf(Ps32, us, cs) : cs;

        // exclusive value = state entering my chunk; lane0 <- carried state
        float ex_f = __shfl_up(cf, 1), ex_s = __shfl_up(cs, 1);
        if (lane == 0) { ex_f = sfr; ex_s = ssr; }
        // state after this tile (broadcast from lane 63)
        sfr = __shfl(cf, 63);
        ssr = __shfl(cs, 63);

        const bool emit = (t >= h);
        float4 s0, s1, s2, s3, s4, s5; float ss;
        if (emit) {
            // ---- phase 2: re-scan with correct state, stage output to LDS ----
            float mf2 = ex_f, ms2 = ex_s;
#pragma unroll
            for (int i = 0; i < K; ++i) {
                float yv = y[i];
                mf2 = fmaf(af, mf2, mu_f * yv);
                ms2 = fmaf(as, ms2, mu_s * yv);
                float M = fmaf(wa, mf2, wb * ms2);
                float o = yv * __builtin_amdgcn_rcpf(EPS_V + M) + whp * (yv - M);
                buf[lane * K + i] = o;                 // overwrite consumed input tile
            }
            asm volatile("s_waitcnt lgkmcnt(0)" ::: "memory");  // cross-lane flush

            // ---- read transposed outputs back to regs (before commit clobbers) --
            const float4* o4 = (const float4*)buf;
            s0 = o4[0 * 64 + lane]; s1 = o4[1 * 64 + lane]; s2 = o4[2 * 64 + lane];
            s3 = o4[3 * 64 + lane]; s4 = o4[4 * 64 + lane]; s5 = o4[5 * 64 + lane];
            ss = buf[1536 + lane];
        }

        // ---- commit prefetched tile t+1 (vmcnt wait covers ONLY the loads;
        //      this tile's stores haven't been issued yet) ----
        if (pref) {
            float4* i4 = (float4*)buf;
            i4[0 * 64 + lane] = p0; i4[1 * 64 + lane] = p1; i4[2 * 64 + lane] = p2;
            i4[3 * 64 + lane] = p3; i4[4 * 64 + lane] = p4; i4[5 * 64 + lane] = p5;
            buf[1536 + lane] = ps;
        }

        // ---- coalesced store, issued last ----
        if (emit) {
            float* gout = oseg + (size_t)t * WTILE;
            float4* go4 = (float4*)gout;
            go4[0 * 64 + lane] = s0;
            go4[1 * 64 + lane] = s1;
            go4[2 * 64 + lane] = s2;
            go4[3 * 64 + lane] = s3;
            go4[4 * 64 + lane] = s4;
            go4[5 * 64 + lane] = s5;
            gout[1536 + lane] = ss;
        }
    }
}

extern "C" void kernel_launch(void* const* d_in, const int* in_sizes, int n_in,
                              void* d_out, int out_size, void* d_ws, size_t ws_size,
                              hipStream_t stream) {
    const float* x    = (const float*)d_in[0];
    const float* mu_f = (const float*)d_in[1];
    const float* mu_s = (const float*)d_in[2];
    const float* mwa  = (const float*)d_in[3];
    const float* mhp  = (const float*)d_in[4];
    float* out = (float*)d_out;

    const int rows   = in_sizes[0] / T_LEN;          // 512
    const int blocks = rows * SEGS_W / WPB;          // 1024
    dual_ema_hp_kernel<<<blocks, THREADS, 0, stream>>>(x, mu_f, mu_s, mwa, mhp, out);
}

// Round 3
// 254.178 us; speedup vs baseline: 1.2756x; 1.2687x over previous
//
#include <hip/hip_runtime.h>

// DualTimeConstantHighPassMixAdaptation on MI355X (gfx950)
// x: [B=8, C=64, T=64000] fp32. 512 independent dual-EMA scans along T.
//
// R6: fit 64 VGPRs genuinely (no spills) instead of fighting the allocator.
// R4/R5 post-mortem: allocator pinned 64-reg band regardless of
// launch_bounds/waves_per_eu attrs; live set ~105 -> 20 floats/lane/tile
// spilled -> +174 MB HBM writes. Fix = cut true pressure:
//  - No s[25] store batch: stores issue chunk-wise from LDS read-back
//    BEFORE the commit; commit's load-wait is counted vmcnt(7) (loads are
//    FIFO-older than the stores) so stores don't stall it.
//  - No persistent y[25]: phase 1 streams from LDS; phase 2 RE-READS from
//    LDS (stride-25 = conflict-free). The memory-clobber lgkmcnt asm
//    between phases doubles as a CSE barrier.
//  - All wave-uniform constants (mu/af/as/wa/whp + 12 scan powers) forced
//    to SGPR via readfirstlane (~19 VGPRs freed).
// Structure otherwise = R3 pipeline at SEGS_W=8: single wave-private LDS
// tile (6.4 KB), register prefetch of tile t+1, zero __syncthreads.
// Grid 1024 = 4 blocks/CU = 16 waves/CU (LDS 102.4 KB/CU).

#define THREADS 256
#define WPB 4                     // waves per block
#define K 25                      // floats per lane per tile
#define WTILE (64 * K)            // 1600 floats = 6.4 KB per wave-tile
#define T_LEN 64000
#define SEGS_W 8
#define SEG_LEN (T_LEN / SEGS_W)  // 8000 floats
#define SEG_TILES (SEG_LEN / WTILE) // 5
#define HALO_TILES 4              // 6400-sample halo (a_slow^6400 ~ 1.3e-3)
#define EPS_V 1e-6f

// force a wave-uniform float into an SGPR
__device__ __forceinline__ float rfl(float v) {
    return __int_as_float(__builtin_amdgcn_readfirstlane(__float_as_int(v)));
}

__global__ __launch_bounds__(THREADS, 4)
void dual_ema_hp_kernel(const float* __restrict__ x,
                        const float* __restrict__ p_mu_fast,
                        const float* __restrict__ p_mu_slow,
                        const float* __restrict__ p_mwa,
                        const float* __restrict__ p_mhp,
                        float* __restrict__ out)
{
    __shared__ float lds[WPB * WTILE];       // 25.6 KB/block
    const int tid  = threadIdx.x;
    const int lane = tid & 63;
    const int wv   = tid >> 6;
    float* buf = &lds[wv * WTILE];           // wave-private tile (in AND out staging)

    const int gw  = blockIdx.x * WPB + wv;
    const int row = gw / SEGS_W;
    const int seg = gw % SEGS_W;
    const int h   = (seg == 0) ? 0 : HALO_TILES;
    const int nt  = SEG_TILES + h;

    const float* gseg = x   + (size_t)row * T_LEN + (size_t)seg * SEG_LEN - (size_t)h * WTILE;
    float*       oseg = out + (size_t)row * T_LEN + (size_t)seg * SEG_LEN - (size_t)h * WTILE;

    // ---- wave-uniform constants -> SGPRs ----
    const float mu_f = rfl(p_mu_fast[0]);
    const float mu_s = rfl(p_mu_slow[0]);
    const float af = rfl(1.0f - mu_f);
    const float as = rfl(1.0f - mu_s);
    const float wa  = rfl(1.0f / (1.0f + __expf(-p_mwa[0])));   // sigmoid(mwa)
    const float wb  = rfl(1.0f - wa);
    const float whp = rfl(1.0f / (1.0f + __expf(-p_mhp[0])));   // sigmoid(mhp)

    // chunk decay (25 samples) + powers for the shfl_up scan
    const float Pf1  = rfl(__powf(af, (float)K));
    const float Ps1  = rfl(__powf(as, (float)K));
    const float Pf2  = rfl(Pf1 * Pf1),   Ps2  = rfl(Ps1 * Ps1);
    const float Pf4  = rfl(Pf2 * Pf2),   Ps4  = rfl(Ps2 * Ps2);
    const float Pf8  = rfl(Pf4 * Pf4),   Ps8  = rfl(Ps4 * Ps4);
    const float Pf16 = rfl(Pf8 * Pf8),   Ps16 = rfl(Ps8 * Ps8);
    const float Pf32 = rfl(Pf16 * Pf16), Ps32 = rfl(Ps16 * Ps16);

    // ---- prologue: load tile 0 coalesced into regs, stage to LDS ----
    float4 p0, p1, p2, p3, p4, p5; float ps;
    {
        const float4* g4 = (const float4*)gseg;
        p0 = g4[0 * 64 + lane]; p1 = g4[1 * 64 + lane]; p2 = g4[2 * 64 + lane];
        p3 = g4[3 * 64 + lane]; p4 = g4[4 * 64 + lane]; p5 = g4[5 * 64 + lane];
        ps = gseg[1536 + lane];
    }
    {
        float4* i4 = (float4*)buf;
        i4[0 * 64 + lane] = p0; i4[1 * 64 + lane] = p1; i4[2 * 64 + lane] = p2;
        i4[3 * 64 + lane] = p3; i4[4 * 64 + lane] = p4; i4[5 * 64 + lane] = p5;
        buf[1536 + lane] = ps;
    }

    float sfr = 0.0f, ssr = 0.0f;   // wave's carried EMA state (zero at halo start)

    for (int t = 0; t < nt; ++t) {
        // ---- make prev ds_writes visible (same-wave in-order LDS pipe) ----
        asm volatile("s_waitcnt lgkmcnt(0)" ::: "memory");

        // first sample of the whole row: init-at-first-sample == seed y0
        if (seg == 0 && t == 0 && lane == 0) {
            float y0 = fmaxf(buf[0], 0.0f);
            sfr = y0; ssr = y0;
        }

        // ---- issue prefetch for tile t+1 (regs; committed at loop end) ----
        const bool pref = (t + 1 < nt);
        if (pref) {
            const float* gt = gseg + (size_t)(t + 1) * WTILE;
            const float4* g4 = (const float4*)gt;
            p0 = g4[0 * 64 + lane]; p1 = g4[1 * 64 + lane]; p2 = g4[2 * 64 + lane];
            p3 = g4[3 * 64 + lane]; p4 = g4[4 * 64 + lane]; p5 = g4[5 * 64 + lane];
            ps = gt[1536 + lane];
        }

        // ---- phase 1: per-lane local scan, streamed from LDS (no y[] array) ----
        float inf = (lane == 0) ? sfr : 0.0f;
        float ins = (lane == 0) ? ssr : 0.0f;
        float mf, ms;
        {
            float yv = fmaxf(buf[lane * K], 0.0f);   // stride 25: conflict-free
            mf = fmaf(af, inf, mu_f * yv);
            ms = fmaf(as, ins, mu_s * yv);
        }
#pragma unroll
        for (int i = 1; i < K; ++i) {
            float yv = fmaxf(buf[lane * K + i], 0.0f);
            mf = fmaf(af, mf, mu_f * yv);
            ms = fmaf(as, ms, mu_s * yv);
        }

        // ---- wave inclusive scan of carries: S_l = c_l + P * S_{l-1} ----
        float cf = mf, cs = ms, uf, us;
        uf = __shfl_up(cf, 1);  us = __shfl_up(cs, 1);
        cf = (lane >= 1)  ? fmaf(Pf1,  uf, cf) : cf;  cs = (lane >= 1)  ? fmaf(Ps1,  us, cs) : cs;
        uf = __shfl_up(cf, 2);  us = __shfl_up(cs, 2);
        cf = (lane >= 2)  ? fmaf(Pf2,  uf, cf) : cf;  cs = (lane >= 2)  ? fmaf(Ps2,  us, cs) : cs;
        uf = __shfl_up(cf, 4);  us = __shfl_up(cs, 4);
        cf = (lane >= 4)  ? fmaf(Pf4,  uf, cf) : cf;  cs = (lane >= 4)  ? fmaf(Ps4,  us, cs) : cs;
        uf = __shfl_up(cf, 8);  us = __shfl_up(cs, 8);
        cf = (lane >= 8)  ? fmaf(Pf8,  uf, cf) : cf;  cs = (lane >= 8)  ? fmaf(Ps8,  us, cs) : cs;
        uf = __shfl_up(cf, 16); us = __shfl_up(cs, 16);
        cf = (lane >= 16) ? fmaf(Pf16, uf, cf) : cf;  cs = (lane >= 16) ? fmaf(Ps16, us, cs) : cs;
        uf = __shfl_up(cf, 32); us = __shfl_up(cs, 32);
        cf = (lane >= 32) ? fmaf(Pf32, uf, cf) : cf;  cs = (lane >= 32) ? fmaf(Ps32, us, cs) : cs;

        // exclusive value = state entering my chunk; lane0 <- carried state
        float ex_f = __shfl_up(cf, 1), ex_s = __shfl_up(cs, 1);
        if (lane == 0) { ex_f = sfr; ex_s = ssr; }
        // state after this tile (broadcast from lane 63)
        sfr = __shfl(cf, 63);
        ssr = __shfl(cs, 63);

        // CSE barrier: forces phase 2 to re-read LDS instead of keeping 25
        // values live across the scan. lgkm queue is empty here -> free.
        asm volatile("s_waitcnt lgkmcnt(0)" ::: "memory");

        const bool emit = (t >= h);
        if (emit) {
            // ---- phase 2: re-scan with correct state, re-reading inputs ----
            float mf2 = ex_f, ms2 = ex_s;
#pragma unroll
            for (int i = 0; i < K; ++i) {
                float yv = fmaxf(buf[lane * K + i], 0.0f);
                mf2 = fmaf(af, mf2, mu_f * yv);
                ms2 = fmaf(as, ms2, mu_s * yv);
                float M = fmaf(wa, mf2, wb * ms2);
                float o = yv * __builtin_amdgcn_rcpf(EPS_V + M) + whp * (yv - M);
                buf[lane * K + i] = o;                 // overwrite consumed input
            }
            asm volatile("s_waitcnt lgkmcnt(0)" ::: "memory");  // cross-lane flush

            // ---- read-back + store, chunk-wise (no register batch) ----
            float* gout = oseg + (size_t)t * WTILE;
            float4* go4 = (float4*)gout;
            const float4* o4 = (const float4*)buf;
#pragma unroll
            for (int c = 0; c < 6; ++c)
                go4[c * 64 + lane] = o4[c * 64 + lane];
            gout[1536 + lane] = buf[1536 + lane];
        }

        // ---- commit prefetched tile t+1 (in-order LDS pipe: ds_writes follow
        //      the read-back ds_reads; load-wait is counted vmcnt, stores
        //      issued above are newer and don't stall it) ----
        if (pref) {
            float4* i4 = (float4*)buf;
            i4[0 * 64 + lane] = p0; i4[1 * 64 + lane] = p1; i4[2 * 64 + lane] = p2;
            i4[3 * 64 + lane] = p3; i4[4 * 64 + lane] = p4; i4[5 * 64 + lane] = p5;
            buf[1536 + lane] = ps;
        }
    }
}

extern "C" void kernel_launch(void* const* d_in, const int* in_sizes, int n_in,
                              void* d_out, int out_size, void* d_ws, size_t ws_size,
                              hipStream_t stream) {
    const float* x    = (const float*)d_in[0];
    const float* mu_f = (const float*)d_in[1];
    const float* mu_s = (const float*)d_in[2];
    const float* mwa  = (const float*)d_in[3];
    const float* mhp  = (const float*)d_in[4];
    float* out = (float*)d_out;

    const int rows   = in_sizes[0] / T_LEN;          // 512
    const int blocks = rows * SEGS_W / WPB;          // 1024
    dual_ema_hp_kernel<<<blocks, THREADS, 0, stream>>>(x, mu_f, mu_s, mwa, mhp, out);
}

// Round 5
// 251.356 us; speedup vs baseline: 1.2899x; 1.0112x over previous
//
#include <hip/hip_runtime.h>

// DualTimeConstantHighPassMixAdaptation on MI355X (gfx950)
// x: [B=8, C=64, T=64000] fp32. 512 independent dual-EMA scans along T.
//
// R8 = R7 with the compile fix: __builtin_nontemporal_store requires a
// NATIVE vector type (ext_vector_type), not HIP's float4 class. Theory
// unchanged from R7:
// R6 post-mortem: spills gone (WRITE back to 128 MB, VGPR 40) but dur stuck
// at ~91 us/dispatch. Little's law: 4096 waves x ~7KB prefetch = 28 MB
// outstanding / 2.6 TB/s = 10.8 us == measured per-tile wall (91.7/9).
// Memory subsystem is the ceiling at effective ~3.8 TB/s, not 6.3 TB/s.
// Cause: LLC capacity thrash -- x (131 MB) + output (128 MB) = 259 MB >
// 256 MB Infinity Cache; output evicts x -> 107 MB/dispatch x re-fetch
// from HBM (measured FETCH).
// Fix: output has zero temporal locality -> nt-bit stores so output lines
// evict first and x stays LLC-resident; halo re-reads become LLC hits.
// Structure otherwise identical to R6:
//  - 64-VGPR fit: no y[25]/s[25] arrays, phase 2 re-reads LDS; uniform
//    constants in SGPRs via readfirstlane.
//  - Single wave-private 6.4 KB LDS tile; zero __syncthreads; register
//    prefetch of tile t+1; counted vmcnt covers loads only.
//  - SEGS_W=8: 1024 blocks = 4 blocks/CU = 16 waves/CU.

#define THREADS 256
#define WPB 4                     // waves per block
#define K 25                      // floats per lane per tile
#define WTILE (64 * K)            // 1600 floats = 6.4 KB per wave-tile
#define T_LEN 64000
#define SEGS_W 8
#define SEG_LEN (T_LEN / SEGS_W)  // 8000 floats
#define SEG_TILES (SEG_LEN / WTILE) // 5
#define HALO_TILES 4              // 6400-sample halo (a_slow^6400 ~ 1.3e-3)
#define EPS_V 1e-6f

typedef float nfloat4 __attribute__((ext_vector_type(4)));  // native vec for nt builtins

// force a wave-uniform float into an SGPR
__device__ __forceinline__ float rfl(float v) {
    return __int_as_float(__builtin_amdgcn_readfirstlane(__float_as_int(v)));
}

__global__ __launch_bounds__(THREADS, 4)
void dual_ema_hp_kernel(const float* __restrict__ x,
                        const float* __restrict__ p_mu_fast,
                        const float* __restrict__ p_mu_slow,
                        const float* __restrict__ p_mwa,
                        const float* __restrict__ p_mhp,
                        float* __restrict__ out)
{
    __shared__ float lds[WPB * WTILE];       // 25.6 KB/block
    const int tid  = threadIdx.x;
    const int lane = tid & 63;
    const int wv   = tid >> 6;
    float* buf = &lds[wv * WTILE];           // wave-private tile (in AND out staging)

    const int gw  = blockIdx.x * WPB + wv;
    const int row = gw / SEGS_W;
    const int seg = gw % SEGS_W;
    const int h   = (seg == 0) ? 0 : HALO_TILES;
    const int nt  = SEG_TILES + h;

    const float* gseg = x   + (size_t)row * T_LEN + (size_t)seg * SEG_LEN - (size_t)h * WTILE;
    float*       oseg = out + (size_t)row * T_LEN + (size_t)seg * SEG_LEN - (size_t)h * WTILE;

    // ---- wave-uniform constants -> SGPRs ----
    const float mu_f = rfl(p_mu_fast[0]);
    const float mu_s = rfl(p_mu_slow[0]);
    const float af = rfl(1.0f - mu_f);
    const float as = rfl(1.0f - mu_s);
    const float wa  = rfl(1.0f / (1.0f + __expf(-p_mwa[0])));   // sigmoid(mwa)
    const float wb  = rfl(1.0f - wa);
    const float whp = rfl(1.0f / (1.0f + __expf(-p_mhp[0])));   // sigmoid(mhp)

    // chunk decay (25 samples) + powers for the shfl_up scan
    const float Pf1  = rfl(__powf(af, (float)K));
    const float Ps1  = rfl(__powf(as, (float)K));
    const float Pf2  = rfl(Pf1 * Pf1),   Ps2  = rfl(Ps1 * Ps1);
    const float Pf4  = rfl(Pf2 * Pf2),   Ps4  = rfl(Ps2 * Ps2);
    const float Pf8  = rfl(Pf4 * Pf4),   Ps8  = rfl(Ps4 * Ps4);
    const float Pf16 = rfl(Pf8 * Pf8),   Ps16 = rfl(Ps8 * Ps8);
    const float Pf32 = rfl(Pf16 * Pf16), Ps32 = rfl(Ps16 * Ps16);

    // ---- prologue: load tile 0 coalesced into regs, stage to LDS ----
    float4 p0, p1, p2, p3, p4, p5; float ps;
    {
        const float4* g4 = (const float4*)gseg;
        p0 = g4[0 * 64 + lane]; p1 = g4[1 * 64 + lane]; p2 = g4[2 * 64 + lane];
        p3 = g4[3 * 64 + lane]; p4 = g4[4 * 64 + lane]; p5 = g4[5 * 64 + lane];
        ps = gseg[1536 + lane];
    }
    {
        float4* i4 = (float4*)buf;
        i4[0 * 64 + lane] = p0; i4[1 * 64 + lane] = p1; i4[2 * 64 + lane] = p2;
        i4[3 * 64 + lane] = p3; i4[4 * 64 + lane] = p4; i4[5 * 64 + lane] = p5;
        buf[1536 + lane] = ps;
    }

    float sfr = 0.0f, ssr = 0.0f;   // wave's carried EMA state (zero at halo start)

    for (int t = 0; t < nt; ++t) {
        // ---- make prev ds_writes visible (same-wave in-order LDS pipe) ----
        asm volatile("s_waitcnt lgkmcnt(0)" ::: "memory");

        // first sample of the whole row: init-at-first-sample == seed y0
        if (seg == 0 && t == 0 && lane == 0) {
            float y0 = fmaxf(buf[0], 0.0f);
            sfr = y0; ssr = y0;
        }

        // ---- issue prefetch for tile t+1 (regs; committed at loop end) ----
        const bool pref = (t + 1 < nt);
        if (pref) {
            const float* gt = gseg + (size_t)(t + 1) * WTILE;
            const float4* g4 = (const float4*)gt;
            p0 = g4[0 * 64 + lane]; p1 = g4[1 * 64 + lane]; p2 = g4[2 * 64 + lane];
            p3 = g4[3 * 64 + lane]; p4 = g4[4 * 64 + lane]; p5 = g4[5 * 64 + lane];
            ps = gt[1536 + lane];
        }

        // ---- phase 1: per-lane local scan, streamed from LDS (no y[] array) ----
        float inf = (lane == 0) ? sfr : 0.0f;
        float ins = (lane == 0) ? ssr : 0.0f;
        float mf, ms;
        {
            float yv = fmaxf(buf[lane * K], 0.0f);   // stride 25: conflict-free
            mf = fmaf(af, inf, mu_f * yv);
            ms = fmaf(as, ins, mu_s * yv);
        }
#pragma unroll
        for (int i = 1; i < K; ++i) {
            float yv = fmaxf(buf[lane * K + i], 0.0f);
            mf = fmaf(af, mf, mu_f * yv);
            ms = fmaf(as, ms, mu_s * yv);
        }

        // ---- wave inclusive scan of carries: S_l = c_l + P * S_{l-1} ----
        float cf = mf, cs = ms, uf, us;
        uf = __shfl_up(cf, 1);  us = __shfl_up(cs, 1);
        cf = (lane >= 1)  ? fmaf(Pf1,  uf, cf) : cf;  cs = (lane >= 1)  ? fmaf(Ps1,  us, cs) : cs;
        uf = __shfl_up(cf, 2);  us = __shfl_up(cs, 2);
        cf = (lane >= 2)  ? fmaf(Pf2,  uf, cf) : cf;  cs = (lane >= 2)  ? fmaf(Ps2,  us, cs) : cs;
        uf = __shfl_up(cf, 4);  us = __shfl_up(cs, 4);
        cf = (lane >= 4)  ? fmaf(Pf4,  uf, cf) : cf;  cs = (lane >= 4)  ? fmaf(Ps4,  us, cs) : cs;
        uf = __shfl_up(cf, 8);  us = __shfl_up(cs, 8);
        cf = (lane >= 8)  ? fmaf(Pf8,  uf, cf) : cf;  cs = (lane >= 8)  ? fmaf(Ps8,  us, cs) : cs;
        uf = __shfl_up(cf, 16); us = __shfl_up(cs, 16);
        cf = (lane >= 16) ? fmaf(Pf16, uf, cf) : cf;  cs = (lane >= 16) ? fmaf(Ps16, us, cs) : cs;
        uf = __shfl_up(cf, 32); us = __shfl_up(cs, 32);
        cf = (lane >= 32) ? fmaf(Pf32, uf, cf) : cf;  cs = (lane >= 32) ? fmaf(Ps32, us, cs) : cs;

        // exclusive value = state entering my chunk; lane0 <- carried state
        float ex_f = __shfl_up(cf, 1), ex_s = __shfl_up(cs, 1);
        if (lane == 0) { ex_f = sfr; ex_s = ssr; }
        // state after this tile (broadcast from lane 63)
        sfr = __shfl(cf, 63);
        ssr = __shfl(cs, 63);

        // CSE barrier: forces phase 2 to re-read LDS instead of keeping 25
        // values live across the scan. lgkm queue is empty here -> free.
        asm volatile("s_waitcnt lgkmcnt(0)" ::: "memory");

        const bool emit = (t >= h);
        if (emit) {
            // ---- phase 2: re-scan with correct state, re-reading inputs ----
            float mf2 = ex_f, ms2 = ex_s;
#pragma unroll
            for (int i = 0; i < K; ++i) {
                float yv = fmaxf(buf[lane * K + i], 0.0f);
                mf2 = fmaf(af, mf2, mu_f * yv);
                ms2 = fmaf(as, ms2, mu_s * yv);
                float M = fmaf(wa, mf2, wb * ms2);
                float o = yv * __builtin_amdgcn_rcpf(EPS_V + M) + whp * (yv - M);
                buf[lane * K + i] = o;                 // overwrite consumed input
            }
            asm volatile("s_waitcnt lgkmcnt(0)" ::: "memory");  // cross-lane flush

            // ---- read-back + nt store, chunk-wise (no register batch) ----
            float* gout = oseg + (size_t)t * WTILE;
            nfloat4* go4 = (nfloat4*)gout;
            const nfloat4* o4 = (const nfloat4*)buf;
#pragma unroll
            for (int c = 0; c < 6; ++c) {
                nfloat4 v = o4[c * 64 + lane];
                __builtin_nontemporal_store(v, &go4[c * 64 + lane]);
            }
            __builtin_nontemporal_store(buf[1536 + lane], &gout[1536 + lane]);
        }

        // ---- commit prefetched tile t+1 (in-order LDS pipe: ds_writes follow
        //      the read-back ds_reads; load-wait is counted vmcnt, stores
        //      issued above are newer and don't stall it) ----
        if (pref) {
            float4* i4 = (float4*)buf;
            i4[0 * 64 + lane] = p0; i4[1 * 64 + lane] = p1; i4[2 * 64 + lane] = p2;
            i4[3 * 64 + lane] = p3; i4[4 * 64 + lane] = p4; i4[5 * 64 + lane] = p5;
            buf[1536 + lane] = ps;
        }
    }
}

extern "C" void kernel_launch(void* const* d_in, const int* in_sizes, int n_in,
                              void* d_out, int out_size, void* d_ws, size_t ws_size,
                              hipStream_t stream) {
    const float* x    = (const float*)d_in[0];
    const float* mu_f = (const float*)d_in[1];
    const float* mu_s = (const float*)d_in[2];
    const float* mwa  = (const float*)d_in[3];
    const float* mhp  = (const float*)d_in[4];
    float* out = (float*)d_out;

    const int rows   = in_sizes[0] / T_LEN;          // 512
    const int blocks = rows * SEGS_W / WPB;          // 1024
    dual_ema_hp_kernel<<<blocks, THREADS, 0, stream>>>(x, mu_f, mu_s, mwa, mhp, out);
}